// Round 3
// baseline (227.898 us; speedup 1.0000x reference)
//
#include <hip/hip_runtime.h>
#include <hip/hip_fp16.h>
#include <cstdint>
#include <cstddef>

// ---------------------------------------------------------------------------
// SelfAttentionV2: out = softmax((x Wq + bq)(x Wk + bk)^T / 32) (x Wv + bv)
// N=4096, D=1024. fp32 in/out, fp16 MFMA internal.
// R15: R14 measured serial (44.6us, MfmaUtil 28%): per-phase ds_reads +
//   lgkmcnt(0) drain = reads never overlap MFMA (m218: T3's gain IS T4).
//   gemm256_core v2: reads issued ONE PHASE EARLY, compiler-managed counted
//   lgkm waits (no inline lgkm asm), so each MFMA cluster runs with the
//   next phase's 4-12 ds_reads in flight:
//     prologue: read afA(G0),b0(G1) of tile0
//     p0: read b1(T)   | stage G2(T+1) | bar | MFMA q00(afA,b0) | bar
//     p1: read afB(T)  | stage G3(T+1) | bar | MFMA q01(afA,b1) | bar
//     p2: vmcnt(4); read afA_n(T+1,G0) | stage G0(T+2) | bar | MFMA q10(afB,b0) | bar
//     p3: read b0_n(T+1,G1) | stage G1(T+2) | bar | MFMA q11(afB,b1) | vmcnt(4) | bar
//   A ping-pong (afA/afB) costs +32 VGPR; addressing slimmed to 32-bit
//   offsets (saddr staging) to stay <=256 unified regs at 2 waves/SIMD.
//   vmcnt ledger: enter tile w/ 4 outstanding; p2 vmcnt(4) retires G0,G1(T+1)
//   (guards read-ahead); end vmcnt(4) retires G2,G3(T+1); drain-0 only at
//   T=ktiles-2. All stages land >=2 barriers after last read of their rows.
//   prep/qkv/combine_v/add_inv verbatim R14.
// ---------------------------------------------------------------------------

#define NTOK 4096
#define DIM  1024

typedef _Float16 half8  __attribute__((ext_vector_type(8)));
typedef _Float16 half4v __attribute__((ext_vector_type(4)));
typedef float    floatx4 __attribute__((ext_vector_type(4)));

#define GLOBAL_AS __attribute__((address_space(1)))
#define LDS_AS    __attribute__((address_space(3)))

__device__ __forceinline__ void lds_load16(const _Float16* gsrc, _Float16* ldst) {
    __builtin_amdgcn_global_load_lds((GLOBAL_AS void*)gsrc, (LDS_AS void*)ldst, 16, 0, 0);
}

// ---------------------------------------------------------------------------
// WIDE 4-WAVE NT GEMM core (verbatim R4/R9/R11, verified) — used by qkv.
// ---------------------------------------------------------------------------
__device__ __forceinline__ void gemm_wide_core(const _Float16* __restrict__ A,
                                               const _Float16* __restrict__ B,
                                               int K, int lda, int ldb,
                                               int m0, int n0,
                                               _Float16* ldsA, _Float16* ldsB,
                                               floatx4 acc[4][8])
{
    const int t    = threadIdx.x;
    const int lane = t & 63;
    const int wid  = t >> 6;
    const int wm   = (wid >> 1) * 64;
    const int wn   = (wid & 1) * 128;
    const int lrow = lane & 15;
    const int q    = lane >> 4;
    const int xk   = lrow & 7;

    const _Float16* asrc[4]; _Float16* adst[4];
    const _Float16* bsrc[8]; _Float16* bdst[8];
    #pragma unroll
    for (int i = 0; i < 4; ++i) {
        const int p = t + 256 * i, row = p >> 3;
        const int col = ((p & 7) ^ (row & 7)) * 8;
        asrc[i] = A + (size_t)(m0 + row) * lda + col;
        adst[i] = ldsA + p * 8;
    }
    #pragma unroll
    for (int i = 0; i < 8; ++i) {
        const int p = t + 256 * i, row = p >> 3;
        const int col = ((p & 7) ^ (row & 7)) * 8;
        bsrc[i] = B + (size_t)(n0 + row) * ldb + col;
        bdst[i] = ldsB + p * 8;
    }

    const _Float16* fa = ldsA + (wm + lrow) * 64;
    const _Float16* fb = ldsB + (wn + lrow) * 64;

    for (int k0 = 0; k0 < K; k0 += 64) {
        #pragma unroll
        for (int i = 0; i < 4; ++i) lds_load16(asrc[i] + k0, adst[i]);
        #pragma unroll
        for (int i = 0; i < 8; ++i) lds_load16(bsrc[i] + k0, bdst[i]);
        __syncthreads();

        #pragma unroll
        for (int s = 0; s < 2; ++s) {
            const int co = (((s * 4 + q) ^ xk) * 8);
            half8 af[4], bf[8];
            #pragma unroll
            for (int i = 0; i < 4; ++i) af[i] = *(const half8*)(fa + i * 1024 + co);
            #pragma unroll
            for (int i = 0; i < 8; ++i) bf[i] = *(const half8*)(fb + i * 1024 + co);
            #pragma unroll
            for (int ni = 0; ni < 8; ++ni)
                #pragma unroll
                for (int mi = 0; mi < 4; ++mi)
                    acc[mi][ni] = __builtin_amdgcn_mfma_f32_16x16x32_f16(
                        af[mi], bf[ni], acc[mi][ni], 0, 0, 0);
        }
        __syncthreads();
    }
}

// ---------------------------------------------------------------------------
// 256x256-tile 8-wave 4-phase NT GEMM core, v2: read-ahead + counted waits.
// A: M x K row-major (lda), B: N x K row-major (ldb); C = A.B^T tile at
// (m0,n0). 512 threads. ldsA/ldsB each 2 x 256 x 64 halfs (64 KiB each).
// acc[8][4]: wave (wr=wid>>2, wc=wid&3) owns 128x64 at (wr*128, wc*64).
// ---------------------------------------------------------------------------
__device__ __forceinline__ void gemm256_core(const _Float16* __restrict__ A,
                                             const _Float16* __restrict__ B,
                                             int ktiles, int lda, int ldb,
                                             int m0, int n0,
                                             _Float16* ldsA, _Float16* ldsB,
                                             floatx4 acc[8][4])
{
    const int t    = threadIdx.x;        // 0..511
    const int lane = t & 63;
    const int wr   = (t >> 6) >> 2;      // 0..1
    const int wc   = (t >> 6) & 3;       // 0..3
    const int lrow = lane & 15;
    const int q    = lane >> 4;
    const int xk   = lrow & 7;

    // Stage-group addressing as 32-bit byte offsets (saddr-form staging).
    // p = t + 512*li, gr = p>>3, c8 = p&7.
    // A-G0 rows {[0,64)u[128,192)}, A-G2 = +64; B-G1 rows {32-combs nh0},
    // B-G3 = +32. LDS dst lane-contiguous; XOR swizzle on global source col.
    uint32_t aoff[2][2], boff[2][2];
    _Float16 *adst[2][2], *bdst[2][2];
    #pragma unroll
    for (int li = 0; li < 2; ++li) {
        const int p  = t + 512 * li;
        const int gr = p >> 3, c8 = p & 7;
        const int r0 = (gr & 63) + (gr >> 6) * 128;
        const int r2 = r0 + 64;
        aoff[0][li] = (uint32_t)(((m0 + r0) * (size_t)lda + ((c8 ^ (r0 & 7)) * 8)) * 2);
        aoff[1][li] = (uint32_t)(((m0 + r2) * (size_t)lda + ((c8 ^ (r2 & 7)) * 8)) * 2);
        adst[0][li] = ldsA + r0 * 64 + c8 * 8;
        adst[1][li] = ldsA + r2 * 64 + c8 * 8;
        const int r1 = (gr & 31) + (gr >> 5) * 64;
        const int r3 = r1 + 32;
        boff[0][li] = (uint32_t)(((n0 + r1) * (size_t)ldb + ((c8 ^ (r1 & 7)) * 8)) * 2);
        boff[1][li] = (uint32_t)(((n0 + r3) * (size_t)ldb + ((c8 ^ (r3 & 7)) * 8)) * 2);
        bdst[0][li] = ldsB + r1 * 64 + c8 * 8;
        bdst[1][li] = ldsB + r3 * 64 + c8 * 8;
    }

    const int faoff = (wr * 128 + lrow) * 64;
    const int fboff = (wc * 64 + lrow) * 64;
    const int co0 = (q ^ xk) * 8;            // s=0 fragment column
    const int co1 = ((4 + q) ^ xk) * 8;      // s=1 fragment column

#define STAGE_A(g, T_) do { const uint32_t ko_ = (uint32_t)(T_) * 128; \
        const int bo_ = ((T_) & 1) * 16384; \
        lds_load16((const _Float16*)((const char*)A + aoff[g][0] + ko_), adst[g][0] + bo_); \
        lds_load16((const _Float16*)((const char*)A + aoff[g][1] + ko_), adst[g][1] + bo_); } while (0)
#define STAGE_B(g, T_) do { const uint32_t ko_ = (uint32_t)(T_) * 128; \
        const int bo_ = ((T_) & 1) * 16384; \
        lds_load16((const _Float16*)((const char*)B + boff[g][0] + ko_), bdst[g][0] + bo_); \
        lds_load16((const _Float16*)((const char*)B + boff[g][1] + ko_), bdst[g][1] + bo_); } while (0)

    // Prologue: tile0 (8 loads) + G0/G1 of tile1 (4 loads); retire tile0.
    STAGE_A(0, 0); STAGE_B(0, 0); STAGE_A(1, 0); STAGE_B(1, 0);
    STAGE_A(0, 1); STAGE_B(0, 1);
    asm volatile("s_waitcnt vmcnt(4)" ::: "memory");
    __builtin_amdgcn_s_barrier();

    half8 afA[4][2], afB[4][2], b0[2][2], b1[2][2];

    // Prologue reads: afA (G0 rows) + b0 (G1 rows) of tile 0.
    {
        const _Float16* fA = ldsA + faoff;
        const _Float16* fB = ldsB + fboff;
        #pragma unroll
        for (int mi = 0; mi < 4; ++mi) {
            afA[mi][0] = *(const half8*)(fA + mi * 1024 + co0);
            afA[mi][1] = *(const half8*)(fA + mi * 1024 + co1);
        }
        #pragma unroll
        for (int ni = 0; ni < 2; ++ni) {
            b0[ni][0] = *(const half8*)(fB + ni * 1024 + co0);
            b0[ni][1] = *(const half8*)(fB + ni * 1024 + co1);
        }
    }

    for (int T = 0; T < ktiles; ++T) {
        const _Float16* fA  = ldsA + (T & 1) * 16384 + faoff;
        const _Float16* fB  = ldsB + (T & 1) * 16384 + fboff;
        const _Float16* fAn = ldsA + ((T + 1) & 1) * 16384 + faoff;
        const _Float16* fBn = ldsB + ((T + 1) & 1) * 16384 + fboff;

        // ---- p0: read b1(T) [G3 rows] (for p1); stage G2(T+1).
        #pragma unroll
        for (int ni = 0; ni < 2; ++ni) {
            b1[ni][0] = *(const half8*)(fB + 2048 + ni * 1024 + co0);
            b1[ni][1] = *(const half8*)(fB + 2048 + ni * 1024 + co1);
        }
        if (T + 1 < ktiles) STAGE_A(1, T + 1);
        __builtin_amdgcn_s_barrier();
        __builtin_amdgcn_s_setprio(1);
        #pragma unroll
        for (int ni = 0; ni < 2; ++ni)
            #pragma unroll
            for (int mi = 0; mi < 4; ++mi) {
                acc[mi][ni] = __builtin_amdgcn_mfma_f32_16x16x32_f16(
                    afA[mi][0], b0[ni][0], acc[mi][ni], 0, 0, 0);
                acc[mi][ni] = __builtin_amdgcn_mfma_f32_16x16x32_f16(
                    afA[mi][1], b0[ni][1], acc[mi][ni], 0, 0, 0);
            }
        __builtin_amdgcn_s_setprio(0);
        __builtin_amdgcn_s_barrier();

        // ---- p1: read afB(T) [G2 rows] (for p2); stage G3(T+1).
        #pragma unroll
        for (int mi = 0; mi < 4; ++mi) {
            afB[mi][0] = *(const half8*)(fA + 4096 + mi * 1024 + co0);
            afB[mi][1] = *(const half8*)(fA + 4096 + mi * 1024 + co1);
        }
        if (T + 1 < ktiles) STAGE_B(1, T + 1);
        __builtin_amdgcn_s_barrier();
        __builtin_amdgcn_s_setprio(1);
        #pragma unroll
        for (int ni = 0; ni < 2; ++ni)
            #pragma unroll
            for (int mi = 0; mi < 4; ++mi) {
                acc[mi][2 + ni] = __builtin_amdgcn_mfma_f32_16x16x32_f16(
                    afA[mi][0], b1[ni][0], acc[mi][2 + ni], 0, 0, 0);
                acc[mi][2 + ni] = __builtin_amdgcn_mfma_f32_16x16x32_f16(
                    afA[mi][1], b1[ni][1], acc[mi][2 + ni], 0, 0, 0);
            }
        __builtin_amdgcn_s_setprio(0);
        __builtin_amdgcn_s_barrier();

        // ---- p2: retire G0,G1(T+1); read afA(T+1) [G0 rows, next buf]
        //          (for next p0, reuses afA regs); stage G0(T+2).
        if (T + 1 < ktiles) {
            asm volatile("s_waitcnt vmcnt(4)" ::: "memory");
            #pragma unroll
            for (int mi = 0; mi < 4; ++mi) {
                afA[mi][0] = *(const half8*)(fAn + mi * 1024 + co0);
                afA[mi][1] = *(const half8*)(fAn + mi * 1024 + co1);
            }
        }
        if (T + 2 < ktiles) STAGE_A(0, T + 2);
        __builtin_amdgcn_s_barrier();
        __builtin_amdgcn_s_setprio(1);
        #pragma unroll
        for (int ni = 0; ni < 2; ++ni)
            #pragma unroll
            for (int mi = 0; mi < 4; ++mi) {
                acc[4 + mi][ni] = __builtin_amdgcn_mfma_f32_16x16x32_f16(
                    afB[mi][0], b0[ni][0], acc[4 + mi][ni], 0, 0, 0);
                acc[4 + mi][ni] = __builtin_amdgcn_mfma_f32_16x16x32_f16(
                    afB[mi][1], b0[ni][1], acc[4 + mi][ni], 0, 0, 0);
            }
        __builtin_amdgcn_s_setprio(0);
        __builtin_amdgcn_s_barrier();

        // ---- p3: read b0(T+1) [G1 rows, next buf] (reuses b0 regs);
        //          stage G1(T+2); MFMA q11 runs with 12 reads in flight.
        if (T + 1 < ktiles) {
            #pragma unroll
            for (int ni = 0; ni < 2; ++ni) {
                b0[ni][0] = *(const half8*)(fBn + ni * 1024 + co0);
                b0[ni][1] = *(const half8*)(fBn + ni * 1024 + co1);
            }
        }
        if (T + 2 < ktiles) STAGE_B(0, T + 2);
        __builtin_amdgcn_s_barrier();
        __builtin_amdgcn_s_setprio(1);
        #pragma unroll
        for (int ni = 0; ni < 2; ++ni)
            #pragma unroll
            for (int mi = 0; mi < 4; ++mi) {
                acc[4 + mi][2 + ni] = __builtin_amdgcn_mfma_f32_16x16x32_f16(
                    afB[mi][0], b1[ni][0], acc[4 + mi][2 + ni], 0, 0, 0);
                acc[4 + mi][2 + ni] = __builtin_amdgcn_mfma_f32_16x16x32_f16(
                    afB[mi][1], b1[ni][1], acc[4 + mi][2 + ni], 0, 0, 0);
            }
        __builtin_amdgcn_s_setprio(0);
        // end-of-tile: retire G2,G3(T+1); drain to 0 once at T=ktiles-2.
        if (T + 2 < ktiles) {
            asm volatile("s_waitcnt vmcnt(4)" ::: "memory");
        } else if (T + 1 < ktiles) {
            asm volatile("s_waitcnt vmcnt(0)" ::: "memory");
        }
        __builtin_amdgcn_s_barrier();
    }
#undef STAGE_A
#undef STAGE_B
}

// ---------------------------------------------------------------------------
// K0: prep (verbatim R9 body, grid 3072).
// ---------------------------------------------------------------------------
__global__ void __launch_bounds__(128) prep_kernel(const float* __restrict__ x,
                                                   const float* __restrict__ W0,
                                                   const float* __restrict__ W1,
                                                   const float* __restrict__ W2,
                                                   _Float16* __restrict__ xh,
                                                   _Float16* __restrict__ Wt)
{
    __shared__ float tile[32 * 33];
    const int t = threadIdx.x;
    const int G = gridDim.x;

    for (size_t idx = (size_t)blockIdx.x * 128 + t; idx < (size_t)NTOK * DIM / 4;
         idx += (size_t)G * 128) {
        size_t i = idx * 4;
        float4 v = *(const float4*)(x + i);
        half4v h;
        h[0] = (_Float16)v.x; h[1] = (_Float16)v.y;
        h[2] = (_Float16)v.z; h[3] = (_Float16)v.w;
        *(half4v*)(xh + i) = h;
    }

    const int tx = t & 31, ty = t >> 5;   // ty in [0,4)
    for (int w = blockIdx.x; w < 3072; w += G) {
        const int z = w >> 10, r = w & 1023;
        const int nb = (r & 31) * 32, kb = (r >> 5) * 32;
        const float* W = (z == 0) ? W0 : (z == 1) ? W1 : W2;
        _Float16* outw = Wt + (size_t)z * DIM * DIM;
        #pragma unroll
        for (int i = 0; i < 32; i += 4)
            tile[(ty + i) * 33 + tx] = W[(size_t)(kb + ty + i) * DIM + nb + tx];
        __syncthreads();
        #pragma unroll
        for (int i = 0; i < 32; i += 4)
            outw[(size_t)(nb + ty + i) * DIM + kb + tx] =
                (_Float16)tile[tx * 33 + ty + i];
        __syncthreads();
    }
}

// ---------------------------------------------------------------------------
// K1: QKV mixed-K wide grid (verbatim R9, verified; 512 blocks = 2/CU).
// ---------------------------------------------------------------------------
__global__ void __launch_bounds__(256, 2)
qkv_kernel(const _Float16* __restrict__ xh,
           const _Float16* __restrict__ Wt,
           const float* __restrict__ bq,
           const float* __restrict__ bk,
           const float* __restrict__ bv,
           _Float16* __restrict__ qh,
           _Float16* __restrict__ kh,
           _Float16* __restrict__ vt0,
           _Float16* __restrict__ vt1)
{
    __shared__ _Float16 ldsA[128 * 64];
    __shared__ _Float16 ldsB[256 * 64];

    const int b = blockIdx.x;

    const _Float16* A; const _Float16* B;
    const float* bias; _Float16* outm;
    int m0, n0, ldc, K, kstart; bool bias_by_row, do_bias;

    if (b < 256) {
        const int z = b >> 7;            // 0:q 1:k
        const int g = b & 127;
        const int xcd = g & 7;
        const int j   = g >> 3;          // 0..15
        const int mt  = xcd * 4 + (j & 3);   // 32 m-tiles
        const int nt  = j >> 2;              // 4 n-tiles of 256
        m0 = mt * 128; n0 = nt * 256; ldc = DIM;
        K = DIM; kstart = 0; bias_by_row = false; do_bias = true;
        A = xh;
        B = (z == 0) ? Wt : Wt + DIM * DIM;
        bias = (z == 0) ? bq : bk;
        outm = (z == 0) ? qh : kh;
    } else {
        const int h = (b - 256) >> 7;    // k-half 0/1
        const int g = b & 127;
        const int xcd = g & 7;
        const int j   = g >> 3;          // 0..15
        m0 = xcd * 128;                  // 8 m-tiles (d-dim)
        n0 = j * 256;                    // 16 n-tiles (tokens)
        ldc = NTOK;
        K = DIM / 2; kstart = h * (DIM / 2);
        bias_by_row = true; do_bias = (h == 0);
        A = Wt + 2 * DIM * DIM; B = xh; bias = bv;
        outm = (h == 0) ? vt0 : vt1;
    }

    floatx4 acc[4][8];
    #pragma unroll
    for (int mi = 0; mi < 4; ++mi)
        #pragma unroll
        for (int ni = 0; ni < 8; ++ni)
            #pragma unroll
            for (int r = 0; r < 4; ++r) acc[mi][ni][r] = 0.0f;

    gemm_wide_core(A + kstart, B + kstart, K, DIM, DIM, m0, n0, ldsA, ldsB, acc);

    const int lane = threadIdx.x & 63;
    const int wid  = threadIdx.x >> 6;
    const int wm   = (wid >> 1) * 64;
    const int wn   = (wid & 1) * 128;
    const int lrow = lane & 15;
    const int q    = lane >> 4;
    #pragma unroll
    for (int mi = 0; mi < 4; ++mi) {
        #pragma unroll
        for (int ni = 0; ni < 8; ++ni) {
            const int gm = m0 + wm + mi * 16 + q * 4;
            const int gn = n0 + wn + ni * 16 + lrow;
            const float bcol = (!do_bias || bias_by_row) ? 0.0f : bias[gn];
            #pragma unroll
            for (int r = 0; r < 4; ++r) {
                float bb = do_bias ? (bias_by_row ? bias[gm + r] : bcol) : 0.0f;
                outm[(size_t)(gm + r) * ldc + gn] = (_Float16)(acc[mi][ni][r] + bb);
            }
        }
    }
}

// ---------------------------------------------------------------------------
// K2: combine v partials: vt = vt0 + vt1 (verbatim R9).
// ---------------------------------------------------------------------------
__global__ void __launch_bounds__(256) combine_v(const _Float16* __restrict__ vt0,
                                                 const _Float16* __restrict__ vt1,
                                                 _Float16* __restrict__ vt)
{
    size_t i = ((size_t)blockIdx.x * 256 + threadIdx.x) * 8;
    half8 a = *(const half8*)(vt0 + i);
    half8 b = *(const half8*)(vt1 + i);
    half8 o;
    #pragma unroll
    for (int k = 0; k < 8; ++k) o[k] = (_Float16)((float)a[k] + (float)b[k]);
    *(half8*)(vt + i) = o;
}

// ---------------------------------------------------------------------------
// K3: S-GEMM + fused exp + partial rowsums — 256x256 8-wave core v2.
// grid 256 (16mt x 16ct), XCD-banded, 512 thr, 1 block/CU.
// rowsum partials: 64 per row = 16 ct x 4 waves(wc).
// ---------------------------------------------------------------------------
__global__ void __launch_bounds__(512, 2) s_kernel(const _Float16* __restrict__ qh,
                                                   const _Float16* __restrict__ kh,
                                                   _Float16* __restrict__ P,
                                                   float* __restrict__ rowsum_part)
{
    __shared__ _Float16 ldsA[2 * 256 * 64];   // 64 KiB
    __shared__ _Float16 ldsB[2 * 256 * 64];   // 64 KiB

    const int b   = blockIdx.x;
    const int xcd = b & 7;
    const int j   = b >> 3;              // 0..31
    const int mt  = xcd * 2 + (j & 1);   // 16 m-tiles of 256
    const int ct  = j >> 1;              // 16 n-tiles of 256
    const int m0  = mt * 256;
    const int n0  = ct * 256;

    floatx4 acc[8][4];
    #pragma unroll
    for (int mi = 0; mi < 8; ++mi)
        #pragma unroll
        for (int ni = 0; ni < 4; ++ni)
            #pragma unroll
            for (int r = 0; r < 4; ++r) acc[mi][ni][r] = 0.0f;

    gemm256_core(qh, kh, DIM / 64, DIM, DIM, m0, n0, ldsA, ldsB, acc);

    const int lane = threadIdx.x & 63;
    const int wr   = (threadIdx.x >> 6) >> 2;
    const int wc   = (threadIdx.x >> 6) & 3;
    const int lrow = lane & 15;
    const int q    = lane >> 4;

    #pragma unroll
    for (int mi = 0; mi < 8; ++mi) {
        #pragma unroll
        for (int r = 0; r < 4; ++r) {
            const int gm = m0 + wr * 128 + mi * 16 + q * 4 + r;
            float rs = 0.0f;
            #pragma unroll
            for (int ni = 0; ni < 4; ++ni) {
                const int gn = n0 + wc * 64 + ni * 16 + lrow;
                float e = __expf(acc[mi][ni][r] * 0.03125f - 8.0f);
                P[(size_t)gm * NTOK + gn] = (_Float16)e;
                rs += e;
            }
            rs += __shfl_xor(rs, 1, 64);
            rs += __shfl_xor(rs, 2, 64);
            rs += __shfl_xor(rs, 4, 64);
            rs += __shfl_xor(rs, 8, 64);
            if (lrow == 0) rowsum_part[(size_t)gm * 64 + ct * 4 + wc] = rs;
        }
    }
}

// ---------------------------------------------------------------------------
// K4: PV split-K=4 — 256x256 8-wave core v2. grid 256 (4z x 16mt x 4ct).
// z=0 -> fp32 out raw; z=1..3 -> fp16 partials.
// ---------------------------------------------------------------------------
__global__ void __launch_bounds__(512, 2) pv_kernel(const _Float16* __restrict__ P,
                                                    const _Float16* __restrict__ vt,
                                                    float* __restrict__ out,
                                                    _Float16* __restrict__ P1,
                                                    _Float16* __restrict__ P2,
                                                    _Float16* __restrict__ P3)
{
    __shared__ _Float16 ldsA[2 * 256 * 64];
    __shared__ _Float16 ldsB[2 * 256 * 64];

    const int b   = blockIdx.x;
    const int z   = b >> 6;              // 0..3
    const int g   = b & 63;
    const int xcd = g & 7;
    const int j   = g >> 3;              // 0..7
    const int mt  = xcd * 2 + (j & 1);   // 16 m-tiles of 256 (tokens)
    const int ct  = j >> 1;              // 4 n-tiles of 256 (dim)
    const int m0  = mt * 256;
    const int n0  = ct * 256;
    const int kstart = z * (NTOK / 4);

    floatx4 acc[8][4];
    #pragma unroll
    for (int mi = 0; mi < 8; ++mi)
        #pragma unroll
        for (int ni = 0; ni < 4; ++ni)
            #pragma unroll
            for (int r = 0; r < 4; ++r) acc[mi][ni][r] = 0.0f;

    gemm256_core(P + kstart, vt + kstart, (NTOK / 4) / 64, NTOK, NTOK, m0, n0,
                 ldsA, ldsB, acc);

    const int lane = threadIdx.x & 63;
    const int wr   = (threadIdx.x >> 6) >> 2;
    const int wc   = (threadIdx.x >> 6) & 3;
    const int lrow = lane & 15;
    const int q    = lane >> 4;

    _Float16* ph = (z == 1) ? P1 : (z == 2) ? P2 : P3;
    #pragma unroll
    for (int mi = 0; mi < 8; ++mi) {
        #pragma unroll
        for (int ni = 0; ni < 4; ++ni) {
            const int gm = m0 + wr * 128 + mi * 16 + q * 4;
            const int gn = n0 + wc * 64 + ni * 16 + lrow;
            #pragma unroll
            for (int r = 0; r < 4; ++r) {
                if (z == 0) out[(size_t)(gm + r) * DIM + gn] = acc[mi][ni][r];
                else        ph[(size_t)(gm + r) * DIM + gn] = (_Float16)acc[mi][ni][r];
            }
        }
    }
}

// ---------------------------------------------------------------------------
// K5: out = (out + P1 + P2 + P3) / rowsum. rowsum: 64 partials/row.
// ---------------------------------------------------------------------------
__global__ void __launch_bounds__(128) add_inv_kernel(float* __restrict__ out,
                                                      const _Float16* __restrict__ P1,
                                                      const _Float16* __restrict__ P2,
                                                      const _Float16* __restrict__ P3,
                                                      const float* __restrict__ rowsum_part)
{
    const int row = blockIdx.x;
    const int t = threadIdx.x;
    float v = rowsum_part[(size_t)row * 64 + (t & 63)];
    v += __shfl_xor(v, 32, 64);
    v += __shfl_xor(v, 16, 64);
    v += __shfl_xor(v, 8, 64);
    v += __shfl_xor(v, 4, 64);
    v += __shfl_xor(v, 2, 64);
    v += __shfl_xor(v, 1, 64);
    const float inv = 1.0f / v;

    size_t i = (size_t)row * DIM + (size_t)t * 8;
    #pragma unroll
    for (int h = 0; h < 2; ++h) {
        size_t ii = i + h * 4;
        float4 a = *(const float4*)(out + ii);
        half4v b1 = *(const half4v*)(P1 + ii);
        half4v b2 = *(const half4v*)(P2 + ii);
        half4v b3 = *(const half4v*)(P3 + ii);
        a.x = (a.x + (float)b1[0] + (float)b2[0] + (float)b3[0]) * inv;
        a.y = (a.y + (float)b1[1] + (float)b2[1] + (float)b3[1]) * inv;
        a.z = (a.z + (float)b1[2] + (float)b2[2] + (float)b3[2]) * inv;
        a.w = (a.w + (float)b1[3] + (float)b2[3] + (float)b3[3]) * inv;
        *(float4*)(out + ii) = a;
    }
}

// ---------------------------------------------------------------------------
// launch
// ---------------------------------------------------------------------------
extern "C" void kernel_launch(void* const* d_in, const int* in_sizes, int n_in,
                              void* d_out, int out_size, void* d_ws, size_t ws_size,
                              hipStream_t stream)
{
    const float* x  = (const float*)d_in[0];
    const float* Wq = (const float*)d_in[1];
    const float* Wk = (const float*)d_in[2];
    const float* Wv = (const float*)d_in[3];
    const float* bq = (const float*)d_in[4];
    const float* bk = (const float*)d_in[5];
    const float* bv = (const float*)d_in[6];
    float* out = (float*)d_out;
    char* ws = (char*)d_ws;

    // workspace layout (70 MB peak):
    //   0..8    xh   (dead after QKV)      -> rowsum_part @0 (1 MB, S phase)
    //   8..14   Wt   (dead after QKV)      -> P1 @2..10 (PV phase)
    //  14..22   qh   (dead after S)        -> P2 @11..19
    //  22..30   kh   (dead after S)        -> P3 @20..28
    //  30..38   vt   (alive through PV)
    //  38..46   vt0  (dead after combine; P overwrites in S phase)
    //  46..54   vt1  (dead after combine; P overwrites in S phase)
    //  38..70   P    (written in S, after vt0/vt1 dead)
    _Float16* xh  = (_Float16*)(ws);
    _Float16* Wt  = (_Float16*)(ws + (8ull  << 20));
    _Float16* qh  = (_Float16*)(ws + (14ull << 20));
    _Float16* kh  = (_Float16*)(ws + (22ull << 20));
    _Float16* vt  = (_Float16*)(ws + (30ull << 20));
    _Float16* vt0 = (_Float16*)(ws + (38ull << 20));
    _Float16* vt1 = (_Float16*)(ws + (46ull << 20));
    _Float16* P   = (_Float16*)(ws + (38ull << 20));
    float* rowsum_part = (float*)(ws);
    _Float16* P1  = (_Float16*)(ws + (2ull  << 20));
    _Float16* P2  = (_Float16*)(ws + (11ull << 20));
    _Float16* P3  = (_Float16*)(ws + (20ull << 20));

    prep_kernel<<<dim3(3072), 128, 0, stream>>>(x, Wq, Wk, Wv, xh, Wt);
    qkv_kernel<<<dim3(512), 256, 0, stream>>>(xh, Wt, bq, bk, bv, qh, kh, vt0, vt1);
    combine_v<<<dim3(NTOK * DIM / (256 * 8)), 256, 0, stream>>>(vt0, vt1, vt);
    s_kernel<<<dim3(256), 512, 0, stream>>>(qh, kh, P, rowsum_part);
    pv_kernel<<<dim3(256), 512, 0, stream>>>(P, vt, out, P1, P2, P3);
    add_inv_kernel<<<dim3(NTOK), 128, 0, stream>>>(out, P1, P2, P3, rowsum_part);
}

// Round 4
// 209.413 us; speedup vs baseline: 1.0883x; 1.0883x over previous
//
#include <hip/hip_runtime.h>
#include <hip/hip_fp16.h>
#include <cstdint>
#include <cstddef>

// ---------------------------------------------------------------------------
// SelfAttentionV2: out = softmax((x Wq + bq)(x Wk + bk)^T / 32) (x Wv + bv)
// N=4096, D=1024. fp32 in/out, fp16 MFMA internal.
// R16: post-mortem of R13-R15: R12's 2-phase core had good intra-tile
//   read/MFMA overlap (compiler counted-lgkm) but 0-distance staging
//   (vmcnt drain exposed); R14's 4-phase had counted vmcnt but the
//   barrier+lgkmcnt(0) per phase serialized reads vs MFMA (LDS 1150cyc
//   then MFMA 620cyc per phase, lockstep); R15 added read-ahead regs ->
//   spills (WRITE_SIZE +9MB = scratch). v3 core = both fixes, no new regs:
//   - 256x256 tile, BK=64, 8 waves, dbuf LDS 128KiB (1 block/CU)
//   - ONE region per K-tile: stage(T+1) issued first, then all 24
//     ds_read_b128 + 64 MFMA plain C++ (compiler interleaves, R12-style,
//     frag live-set 48 regs), then vmcnt(0) (waits ~0: loads had a full
//     tile of slack) + barrier. 1 barrier/tile instead of 8.
//   prep/qkv/combine_v/add_inv verbatim R9/R14.
// ---------------------------------------------------------------------------

#define NTOK 4096
#define DIM  1024

typedef _Float16 half8  __attribute__((ext_vector_type(8)));
typedef _Float16 half4v __attribute__((ext_vector_type(4)));
typedef float    floatx4 __attribute__((ext_vector_type(4)));

#define GLOBAL_AS __attribute__((address_space(1)))
#define LDS_AS    __attribute__((address_space(3)))

__device__ __forceinline__ void lds_load16(const _Float16* gsrc, _Float16* ldst) {
    __builtin_amdgcn_global_load_lds((GLOBAL_AS void*)gsrc, (LDS_AS void*)ldst, 16, 0, 0);
}

// ---------------------------------------------------------------------------
// WIDE 4-WAVE NT GEMM core (verbatim R4/R9/R11, verified) — used by qkv.
// ---------------------------------------------------------------------------
__device__ __forceinline__ void gemm_wide_core(const _Float16* __restrict__ A,
                                               const _Float16* __restrict__ B,
                                               int K, int lda, int ldb,
                                               int m0, int n0,
                                               _Float16* ldsA, _Float16* ldsB,
                                               floatx4 acc[4][8])
{
    const int t    = threadIdx.x;
    const int lane = t & 63;
    const int wid  = t >> 6;
    const int wm   = (wid >> 1) * 64;
    const int wn   = (wid & 1) * 128;
    const int lrow = lane & 15;
    const int q    = lane >> 4;
    const int xk   = lrow & 7;

    const _Float16* asrc[4]; _Float16* adst[4];
    const _Float16* bsrc[8]; _Float16* bdst[8];
    #pragma unroll
    for (int i = 0; i < 4; ++i) {
        const int p = t + 256 * i, row = p >> 3;
        const int col = ((p & 7) ^ (row & 7)) * 8;
        asrc[i] = A + (size_t)(m0 + row) * lda + col;
        adst[i] = ldsA + p * 8;
    }
    #pragma unroll
    for (int i = 0; i < 8; ++i) {
        const int p = t + 256 * i, row = p >> 3;
        const int col = ((p & 7) ^ (row & 7)) * 8;
        bsrc[i] = B + (size_t)(n0 + row) * ldb + col;
        bdst[i] = ldsB + p * 8;
    }

    const _Float16* fa = ldsA + (wm + lrow) * 64;
    const _Float16* fb = ldsB + (wn + lrow) * 64;

    for (int k0 = 0; k0 < K; k0 += 64) {
        #pragma unroll
        for (int i = 0; i < 4; ++i) lds_load16(asrc[i] + k0, adst[i]);
        #pragma unroll
        for (int i = 0; i < 8; ++i) lds_load16(bsrc[i] + k0, bdst[i]);
        __syncthreads();

        #pragma unroll
        for (int s = 0; s < 2; ++s) {
            const int co = (((s * 4 + q) ^ xk) * 8);
            half8 af[4], bf[8];
            #pragma unroll
            for (int i = 0; i < 4; ++i) af[i] = *(const half8*)(fa + i * 1024 + co);
            #pragma unroll
            for (int i = 0; i < 8; ++i) bf[i] = *(const half8*)(fb + i * 1024 + co);
            #pragma unroll
            for (int ni = 0; ni < 8; ++ni)
                #pragma unroll
                for (int mi = 0; mi < 4; ++mi)
                    acc[mi][ni] = __builtin_amdgcn_mfma_f32_16x16x32_f16(
                        af[mi], bf[ni], acc[mi][ni], 0, 0, 0);
        }
        __syncthreads();
    }
}

// ---------------------------------------------------------------------------
// 256x256-tile 8-wave NT GEMM core v3: single compiler-scheduled region per
// K-tile + 1-tile staging prefetch + 1 barrier/tile.
// A: M x K row-major (lda), B: N x K row-major (ldb); C = A.B^T tile at
// (m0,n0). 512 threads. ldsA/ldsB each 2 x 256 x 64 halfs (64 KiB each).
// acc[8][4]: wave (wr=wid>>2, wc=wid&3) owns 128x64 at (wr*128, wc*64).
// ---------------------------------------------------------------------------
__device__ __forceinline__ void gemm256_core(const _Float16* __restrict__ A,
                                             const _Float16* __restrict__ B,
                                             int ktiles, int lda, int ldb,
                                             int m0, int n0,
                                             _Float16* ldsA, _Float16* ldsB,
                                             floatx4 acc[8][4])
{
    const int t    = threadIdx.x;        // 0..511
    const int lane = t & 63;
    const int wr   = (t >> 6) >> 2;      // 0..1
    const int wc   = (t >> 6) & 3;       // 0..3
    const int lrow = lane & 15;
    const int q    = lane >> 4;
    const int xk   = lrow & 7;

    // Staging: 8 loads/thread cover A(256x64)+B(256x64)=64KB per K-tile.
    // p = t + 512*i -> row p>>3 (0..255), 8 threads/row, c8 = p&7.
    // LDS dst lane-contiguous (global_load_lds rule); XOR swizzle on the
    // global source column (rule #21, both-sides-or-neither).
    const _Float16* asrc[4]; _Float16* adst[4];
    const _Float16* bsrc[4]; _Float16* bdst[4];
    #pragma unroll
    for (int i = 0; i < 4; ++i) {
        const int p = t + 512 * i, row = p >> 3, c8 = p & 7;
        const int col = (c8 ^ (row & 7)) * 8;
        asrc[i] = A + (size_t)(m0 + row) * lda + col;
        adst[i] = ldsA + row * 64 + c8 * 8;
        bsrc[i] = B + (size_t)(n0 + row) * ldb + col;
        bdst[i] = ldsB + row * 64 + c8 * 8;
    }

    const int faoff = (wr * 128 + lrow) * 64;
    const int fboff = (wc * 64 + lrow) * 64;

#define STAGE(T_) do { const size_t ko_ = (size_t)(T_) * 64; \
        const int bo_ = ((T_) & 1) * 16384; \
        _Pragma("unroll") \
        for (int i_ = 0; i_ < 4; ++i_) { \
            lds_load16(asrc[i_] + ko_, adst[i_] + bo_); \
            lds_load16(bsrc[i_] + ko_, bdst[i_] + bo_); } } while (0)

    // Prologue: stage tile0 cold (exposed once), barrier.
    STAGE(0);
    asm volatile("s_waitcnt vmcnt(0)" ::: "memory");
    __builtin_amdgcn_s_barrier();

    for (int T = 0; T < ktiles; ++T) {
        // Issue next tile's staging FIRST: a full tile (~2500cyc) of slack
        // before the boundary drain. Targets buf[(T+1)&1], whose readers
        // all completed before the end-of-(T-1) barrier.
        if (T + 1 < ktiles) STAGE(T + 1);

        // Single compiler-scheduled region: 24 ds_read_b128 + 64 MFMA.
        // No inline lgkm waits, no intra-tile barriers: the compiler emits
        // counted lgkmcnt and interleaves reads with MFMA (m97-verified).
        const _Float16* fa = ldsA + (T & 1) * 16384 + faoff;
        const _Float16* fb = ldsB + (T & 1) * 16384 + fboff;
        #pragma unroll
        for (int s = 0; s < 2; ++s) {
            const int co = (((s * 4 + q) ^ xk) * 8);
            half8 af[8], bf[4];
            #pragma unroll
            for (int mi = 0; mi < 8; ++mi) af[mi] = *(const half8*)(fa + mi * 1024 + co);
            #pragma unroll
            for (int ni = 0; ni < 4; ++ni) bf[ni] = *(const half8*)(fb + ni * 1024 + co);
            #pragma unroll
            for (int ni = 0; ni < 4; ++ni)
                #pragma unroll
                for (int mi = 0; mi < 8; ++mi)
                    acc[mi][ni] = __builtin_amdgcn_mfma_f32_16x16x32_f16(
                        af[mi], bf[ni], acc[mi][ni], 0, 0, 0);
        }

        // Boundary: drain own stages (near-zero wait: issued a tile ago),
        // then one barrier. Next tile reads what all waves just staged.
        if (T + 1 < ktiles) {
            asm volatile("s_waitcnt vmcnt(0)" ::: "memory");
        }
        __builtin_amdgcn_s_barrier();
    }
#undef STAGE
}

// ---------------------------------------------------------------------------
// K0: prep (verbatim R9 body, grid 3072).
// ---------------------------------------------------------------------------
__global__ void __launch_bounds__(128) prep_kernel(const float* __restrict__ x,
                                                   const float* __restrict__ W0,
                                                   const float* __restrict__ W1,
                                                   const float* __restrict__ W2,
                                                   _Float16* __restrict__ xh,
                                                   _Float16* __restrict__ Wt)
{
    __shared__ float tile[32 * 33];
    const int t = threadIdx.x;
    const int G = gridDim.x;

    for (size_t idx = (size_t)blockIdx.x * 128 + t; idx < (size_t)NTOK * DIM / 4;
         idx += (size_t)G * 128) {
        size_t i = idx * 4;
        float4 v = *(const float4*)(x + i);
        half4v h;
        h[0] = (_Float16)v.x; h[1] = (_Float16)v.y;
        h[2] = (_Float16)v.z; h[3] = (_Float16)v.w;
        *(half4v*)(xh + i) = h;
    }

    const int tx = t & 31, ty = t >> 5;   // ty in [0,4)
    for (int w = blockIdx.x; w < 3072; w += G) {
        const int z = w >> 10, r = w & 1023;
        const int nb = (r & 31) * 32, kb = (r >> 5) * 32;
        const float* W = (z == 0) ? W0 : (z == 1) ? W1 : W2;
        _Float16* outw = Wt + (size_t)z * DIM * DIM;
        #pragma unroll
        for (int i = 0; i < 32; i += 4)
            tile[(ty + i) * 33 + tx] = W[(size_t)(kb + ty + i) * DIM + nb + tx];
        __syncthreads();
        #pragma unroll
        for (int i = 0; i < 32; i += 4)
            outw[(size_t)(nb + ty + i) * DIM + kb + tx] =
                (_Float16)tile[tx * 33 + ty + i];
        __syncthreads();
    }
}

// ---------------------------------------------------------------------------
// K1: QKV mixed-K wide grid (verbatim R9, verified; 512 blocks = 2/CU).
// ---------------------------------------------------------------------------
__global__ void __launch_bounds__(256, 2)
qkv_kernel(const _Float16* __restrict__ xh,
           const _Float16* __restrict__ Wt,
           const float* __restrict__ bq,
           const float* __restrict__ bk,
           const float* __restrict__ bv,
           _Float16* __restrict__ qh,
           _Float16* __restrict__ kh,
           _Float16* __restrict__ vt0,
           _Float16* __restrict__ vt1)
{
    __shared__ _Float16 ldsA[128 * 64];
    __shared__ _Float16 ldsB[256 * 64];

    const int b = blockIdx.x;

    const _Float16* A; const _Float16* B;
    const float* bias; _Float16* outm;
    int m0, n0, ldc, K, kstart; bool bias_by_row, do_bias;

    if (b < 256) {
        const int z = b >> 7;            // 0:q 1:k
        const int g = b & 127;
        const int xcd = g & 7;
        const int j   = g >> 3;          // 0..15
        const int mt  = xcd * 4 + (j & 3);   // 32 m-tiles
        const int nt  = j >> 2;              // 4 n-tiles of 256
        m0 = mt * 128; n0 = nt * 256; ldc = DIM;
        K = DIM; kstart = 0; bias_by_row = false; do_bias = true;
        A = xh;
        B = (z == 0) ? Wt : Wt + DIM * DIM;
        bias = (z == 0) ? bq : bk;
        outm = (z == 0) ? qh : kh;
    } else {
        const int h = (b - 256) >> 7;    // k-half 0/1
        const int g = b & 127;
        const int xcd = g & 7;
        const int j   = g >> 3;          // 0..15
        m0 = xcd * 128;                  // 8 m-tiles (d-dim)
        n0 = j * 256;                    // 16 n-tiles (tokens)
        ldc = NTOK;
        K = DIM / 2; kstart = h * (DIM / 2);
        bias_by_row = true; do_bias = (h == 0);
        A = Wt + 2 * DIM * DIM; B = xh; bias = bv;
        outm = (h == 0) ? vt0 : vt1;
    }

    floatx4 acc[4][8];
    #pragma unroll
    for (int mi = 0; mi < 4; ++mi)
        #pragma unroll
        for (int ni = 0; ni < 8; ++ni)
            #pragma unroll
            for (int r = 0; r < 4; ++r) acc[mi][ni][r] = 0.0f;

    gemm_wide_core(A + kstart, B + kstart, K, DIM, DIM, m0, n0, ldsA, ldsB, acc);

    const int lane = threadIdx.x & 63;
    const int wid  = threadIdx.x >> 6;
    const int wm   = (wid >> 1) * 64;
    const int wn   = (wid & 1) * 128;
    const int lrow = lane & 15;
    const int q    = lane >> 4;
    #pragma unroll
    for (int mi = 0; mi < 4; ++mi) {
        #pragma unroll
        for (int ni = 0; ni < 8; ++ni) {
            const int gm = m0 + wm + mi * 16 + q * 4;
            const int gn = n0 + wn + ni * 16 + lrow;
            const float bcol = (!do_bias || bias_by_row) ? 0.0f : bias[gn];
            #pragma unroll
            for (int r = 0; r < 4; ++r) {
                float bb = do_bias ? (bias_by_row ? bias[gm + r] : bcol) : 0.0f;
                outm[(size_t)(gm + r) * ldc + gn] = (_Float16)(acc[mi][ni][r] + bb);
            }
        }
    }
}

// ---------------------------------------------------------------------------
// K2: combine v partials: vt = vt0 + vt1 (verbatim R9).
// ---------------------------------------------------------------------------
__global__ void __launch_bounds__(256) combine_v(const _Float16* __restrict__ vt0,
                                                 const _Float16* __restrict__ vt1,
                                                 _Float16* __restrict__ vt)
{
    size_t i = ((size_t)blockIdx.x * 256 + threadIdx.x) * 8;
    half8 a = *(const half8*)(vt0 + i);
    half8 b = *(const half8*)(vt1 + i);
    half8 o;
    #pragma unroll
    for (int k = 0; k < 8; ++k) o[k] = (_Float16)((float)a[k] + (float)b[k]);
    *(half8*)(vt + i) = o;
}

// ---------------------------------------------------------------------------
// K3: S-GEMM + fused exp + partial rowsums — 256x256 core v3.
// grid 256 (16mt x 16ct), XCD-banded, 512 thr, 1 block/CU.
// rowsum partials: 64 per row = 16 ct x 4 waves(wc).
// ---------------------------------------------------------------------------
__global__ void __launch_bounds__(512) s_kernel(const _Float16* __restrict__ qh,
                                                const _Float16* __restrict__ kh,
                                                _Float16* __restrict__ P,
                                                float* __restrict__ rowsum_part)
{
    __shared__ _Float16 ldsA[2 * 256 * 64];   // 64 KiB
    __shared__ _Float16 ldsB[2 * 256 * 64];   // 64 KiB

    const int b   = blockIdx.x;
    const int xcd = b & 7;
    const int j   = b >> 3;              // 0..31
    const int mt  = xcd * 2 + (j & 1);   // 16 m-tiles of 256
    const int ct  = j >> 1;              // 16 n-tiles of 256
    const int m0  = mt * 256;
    const int n0  = ct * 256;

    floatx4 acc[8][4];
    #pragma unroll
    for (int mi = 0; mi < 8; ++mi)
        #pragma unroll
        for (int ni = 0; ni < 4; ++ni)
            #pragma unroll
            for (int r = 0; r < 4; ++r) acc[mi][ni][r] = 0.0f;

    gemm256_core(qh, kh, DIM / 64, DIM, DIM, m0, n0, ldsA, ldsB, acc);

    const int lane = threadIdx.x & 63;
    const int wr   = (threadIdx.x >> 6) >> 2;
    const int wc   = (threadIdx.x >> 6) & 3;
    const int lrow = lane & 15;
    const int q    = lane >> 4;

    #pragma unroll
    for (int mi = 0; mi < 8; ++mi) {
        #pragma unroll
        for (int r = 0; r < 4; ++r) {
            const int gm = m0 + wr * 128 + mi * 16 + q * 4 + r;
            float rs = 0.0f;
            #pragma unroll
            for (int ni = 0; ni < 4; ++ni) {
                const int gn = n0 + wc * 64 + ni * 16 + lrow;
                float e = __expf(acc[mi][ni][r] * 0.03125f - 8.0f);
                P[(size_t)gm * NTOK + gn] = (_Float16)e;
                rs += e;
            }
            rs += __shfl_xor(rs, 1, 64);
            rs += __shfl_xor(rs, 2, 64);
            rs += __shfl_xor(rs, 4, 64);
            rs += __shfl_xor(rs, 8, 64);
            if (lrow == 0) rowsum_part[(size_t)gm * 64 + ct * 4 + wc] = rs;
        }
    }
}

// ---------------------------------------------------------------------------
// K4: PV split-K=4 — 256x256 core v3. grid 256 (4z x 16mt x 4ct).
// z=0 -> fp32 out raw; z=1..3 -> fp16 partials.
// ---------------------------------------------------------------------------
__global__ void __launch_bounds__(512) pv_kernel(const _Float16* __restrict__ P,
                                                 const _Float16* __restrict__ vt,
                                                 float* __restrict__ out,
                                                 _Float16* __restrict__ P1,
                                                 _Float16* __restrict__ P2,
                                                 _Float16* __restrict__ P3)
{
    __shared__ _Float16 ldsA[2 * 256 * 64];
    __shared__ _Float16 ldsB[2 * 256 * 64];

    const int b   = blockIdx.x;
    const int z   = b >> 6;              // 0..3
    const int g   = b & 63;
    const int xcd = g & 7;
    const int j   = g >> 3;              // 0..7
    const int mt  = xcd * 2 + (j & 1);   // 16 m-tiles of 256 (tokens)
    const int ct  = j >> 1;              // 4 n-tiles of 256 (dim)
    const int m0  = mt * 256;
    const int n0  = ct * 256;
    const int kstart = z * (NTOK / 4);

    floatx4 acc[8][4];
    #pragma unroll
    for (int mi = 0; mi < 8; ++mi)
        #pragma unroll
        for (int ni = 0; ni < 4; ++ni)
            #pragma unroll
            for (int r = 0; r < 4; ++r) acc[mi][ni][r] = 0.0f;

    gemm256_core(P + kstart, vt + kstart, (NTOK / 4) / 64, NTOK, NTOK, m0, n0,
                 ldsA, ldsB, acc);

    const int lane = threadIdx.x & 63;
    const int wr   = (threadIdx.x >> 6) >> 2;
    const int wc   = (threadIdx.x >> 6) & 3;
    const int lrow = lane & 15;
    const int q    = lane >> 4;

    _Float16* ph = (z == 1) ? P1 : (z == 2) ? P2 : P3;
    #pragma unroll
    for (int mi = 0; mi < 8; ++mi) {
        #pragma unroll
        for (int ni = 0; ni < 4; ++ni) {
            const int gm = m0 + wr * 128 + mi * 16 + q * 4;
            const int gn = n0 + wc * 64 + ni * 16 + lrow;
            #pragma unroll
            for (int r = 0; r < 4; ++r) {
                if (z == 0) out[(size_t)(gm + r) * DIM + gn] = acc[mi][ni][r];
                else        ph[(size_t)(gm + r) * DIM + gn] = (_Float16)acc[mi][ni][r];
            }
        }
    }
}

// ---------------------------------------------------------------------------
// K5: out = (out + P1 + P2 + P3) / rowsum. rowsum: 64 partials/row.
// ---------------------------------------------------------------------------
__global__ void __launch_bounds__(128) add_inv_kernel(float* __restrict__ out,
                                                      const _Float16* __restrict__ P1,
                                                      const _Float16* __restrict__ P2,
                                                      const _Float16* __restrict__ P3,
                                                      const float* __restrict__ rowsum_part)
{
    const int row = blockIdx.x;
    const int t = threadIdx.x;
    float v = rowsum_part[(size_t)row * 64 + (t & 63)];
    v += __shfl_xor(v, 32, 64);
    v += __shfl_xor(v, 16, 64);
    v += __shfl_xor(v, 8, 64);
    v += __shfl_xor(v, 4, 64);
    v += __shfl_xor(v, 2, 64);
    v += __shfl_xor(v, 1, 64);
    const float inv = 1.0f / v;

    size_t i = (size_t)row * DIM + (size_t)t * 8;
    #pragma unroll
    for (int h = 0; h < 2; ++h) {
        size_t ii = i + h * 4;
        float4 a = *(const float4*)(out + ii);
        half4v b1 = *(const half4v*)(P1 + ii);
        half4v b2 = *(const half4v*)(P2 + ii);
        half4v b3 = *(const half4v*)(P3 + ii);
        a.x = (a.x + (float)b1[0] + (float)b2[0] + (float)b3[0]) * inv;
        a.y = (a.y + (float)b1[1] + (float)b2[1] + (float)b3[1]) * inv;
        a.z = (a.z + (float)b1[2] + (float)b2[2] + (float)b3[2]) * inv;
        a.w = (a.w + (float)b1[3] + (float)b2[3] + (float)b3[3]) * inv;
        *(float4*)(out + ii) = a;
    }
}

// ---------------------------------------------------------------------------
// launch
// ---------------------------------------------------------------------------
extern "C" void kernel_launch(void* const* d_in, const int* in_sizes, int n_in,
                              void* d_out, int out_size, void* d_ws, size_t ws_size,
                              hipStream_t stream)
{
    const float* x  = (const float*)d_in[0];
    const float* Wq = (const float*)d_in[1];
    const float* Wk = (const float*)d_in[2];
    const float* Wv = (const float*)d_in[3];
    const float* bq = (const float*)d_in[4];
    const float* bk = (const float*)d_in[5];
    const float* bv = (const float*)d_in[6];
    float* out = (float*)d_out;
    char* ws = (char*)d_ws;

    // workspace layout (70 MB peak):
    //   0..8    xh   (dead after QKV)      -> rowsum_part @0 (1 MB, S phase)
    //   8..14   Wt   (dead after QKV)      -> P1 @2..10 (PV phase)
    //  14..22   qh   (dead after S)        -> P2 @11..19
    //  22..30   kh   (dead after S)        -> P3 @20..28
    //  30..38   vt   (alive through PV)
    //  38..46   vt0  (dead after combine; P overwrites in S phase)
    //  46..54   vt1  (dead after combine; P overwrites in S phase)
    //  38..70   P    (written in S, after vt0/vt1 dead)
    _Float16* xh  = (_Float16*)(ws);
    _Float16* Wt  = (_Float16*)(ws + (8ull  << 20));
    _Float16* qh  = (_Float16*)(ws + (14ull << 20));
    _Float16* kh  = (_Float16*)(ws + (22ull << 20));
    _Float16* vt  = (_Float16*)(ws + (30ull << 20));
    _Float16* vt0 = (_Float16*)(ws + (38ull << 20));
    _Float16* vt1 = (_Float16*)(ws + (46ull << 20));
    _Float16* P   = (_Float16*)(ws + (38ull << 20));
    float* rowsum_part = (float*)(ws);
    _Float16* P1  = (_Float16*)(ws + (2ull  << 20));
    _Float16* P2  = (_Float16*)(ws + (11ull << 20));
    _Float16* P3  = (_Float16*)(ws + (20ull << 20));

    prep_kernel<<<dim3(3072), 128, 0, stream>>>(x, Wq, Wk, Wv, xh, Wt);
    qkv_kernel<<<dim3(512), 256, 0, stream>>>(xh, Wt, bq, bk, bv, qh, kh, vt0, vt1);
    combine_v<<<dim3(NTOK * DIM / (256 * 8)), 256, 0, stream>>>(vt0, vt1, vt);
    s_kernel<<<dim3(256), 512, 0, stream>>>(qh, kh, P, rowsum_part);
    pv_kernel<<<dim3(256), 512, 0, stream>>>(P, vt, out, P1, P2, P3);
    add_inv_kernel<<<dim3(NTOK), 128, 0, stream>>>(out, P1, P2, P3, rowsum_part);
}